// Round 1
// baseline (15280.730 us; speedup 1.0000x reference)
//
#include <hip/hip_runtime.h>
#include <math.h>

// Sizes (fixed by the problem)
#define TSE 48
#define TTD 48
#define BB  64
#define HH  512
#define VV  32000
// 2H=1024, 3H=1536

__device__ __forceinline__ float sigmoidf_(float x) { return 1.0f / (1.0f + expf(-x)); }

// ---------------------------------------------------------------- zero
__global__ __launch_bounds__(256) void zero_f32(float* __restrict__ p, int n) {
    int i = blockIdx.x * 256 + threadIdx.x;
    if (i < n) p[i] = 0.0f;
}

// ---------------------------------------------------------------- embedding gather
// out[row,:] = emb[idx[row],:]  (row length 512 = 128 threads * float4)
__global__ __launch_bounds__(128) void gather_emb(const int* __restrict__ idx,
                                                  const float* __restrict__ emb,
                                                  float* __restrict__ out) {
    int row = blockIdx.x;
    int v = idx[row];
    const float4* s = (const float4*)(emb + (size_t)v * HH);
    float4* d = (float4*)(out + (size_t)row * HH);
    d[threadIdx.x] = s[threadIdx.x];
}

// ---------------------------------------------------------------- generic f32 GEMM
// C[M,N] = A[M,K] @ opB + bias.  TRANSB=1: B is (N,ldb) row-major, use B[n,k].
//                                TRANSB=0: B is (K,ldb) row-major, use B[k,n].
// Requires M%128==0, N%128==0, K%32==0 (true for all call sites).
template <int TRANSB, int BIAS>
__global__ __launch_bounds__(256) void gemm_f32(const float* __restrict__ A,
                                                const float* __restrict__ Bm,
                                                const float* __restrict__ bias,
                                                float* __restrict__ C,
                                                int M, int N, int K, int lda, int ldb, int ldc) {
    __shared__ float As[32][132];
    __shared__ float Bs[32][132];
    const int tid = threadIdx.x;
    const int tx = tid & 15, ty = tid >> 4;
    const int m0 = blockIdx.y * 128, n0 = blockIdx.x * 128;

    float acc[8][8];
#pragma unroll
    for (int i = 0; i < 8; i++)
#pragma unroll
        for (int j = 0; j < 8; j++) acc[i][j] = 0.0f;

    const int arow = tid >> 1, akq = (tid & 1) * 16;   // A/B(transB) loader: 128 rows x 32k
    const int bk = tid >> 3, bnq = (tid & 7) * 16;     // B(noTrans) loader: 32 k x 128 n

    for (int k0 = 0; k0 < K; k0 += 32) {
        float4 av[4], bv[4];
        const float* ap = A + (size_t)(m0 + arow) * lda + k0 + akq;
#pragma unroll
        for (int q = 0; q < 4; q++) av[q] = *(const float4*)(ap + 4 * q);
        if (TRANSB) {
            const float* bp = Bm + (size_t)(n0 + arow) * ldb + k0 + akq;
#pragma unroll
            for (int q = 0; q < 4; q++) bv[q] = *(const float4*)(bp + 4 * q);
        } else {
            const float* bp = Bm + (size_t)(k0 + bk) * ldb + n0 + bnq;
#pragma unroll
            for (int q = 0; q < 4; q++) bv[q] = *(const float4*)(bp + 4 * q);
        }
        __syncthreads();
#pragma unroll
        for (int q = 0; q < 4; q++) {
            As[akq + 4 * q + 0][arow] = av[q].x;
            As[akq + 4 * q + 1][arow] = av[q].y;
            As[akq + 4 * q + 2][arow] = av[q].z;
            As[akq + 4 * q + 3][arow] = av[q].w;
        }
        if (TRANSB) {
#pragma unroll
            for (int q = 0; q < 4; q++) {
                Bs[akq + 4 * q + 0][arow] = bv[q].x;
                Bs[akq + 4 * q + 1][arow] = bv[q].y;
                Bs[akq + 4 * q + 2][arow] = bv[q].z;
                Bs[akq + 4 * q + 3][arow] = bv[q].w;
            }
        } else {
#pragma unroll
            for (int q = 0; q < 4; q++) *(float4*)&Bs[bk][bnq + 4 * q] = bv[q];
        }
        __syncthreads();
#pragma unroll
        for (int kk = 0; kk < 32; kk++) {
            float4 a0 = *(const float4*)&As[kk][ty * 8];
            float4 a1 = *(const float4*)&As[kk][ty * 8 + 4];
            float4 b0 = *(const float4*)&Bs[kk][tx * 8];
            float4 b1 = *(const float4*)&Bs[kk][tx * 8 + 4];
            float aa[8] = {a0.x, a0.y, a0.z, a0.w, a1.x, a1.y, a1.z, a1.w};
            float bb[8] = {b0.x, b0.y, b0.z, b0.w, b1.x, b1.y, b1.z, b1.w};
#pragma unroll
            for (int i = 0; i < 8; i++)
#pragma unroll
                for (int j = 0; j < 8; j++) acc[i][j] += aa[i] * bb[j];
        }
    }

    float bb8[8];
#pragma unroll
    for (int j = 0; j < 8; j++) bb8[j] = BIAS ? bias[n0 + tx * 8 + j] : 0.0f;
#pragma unroll
    for (int i = 0; i < 8; i++) {
        float* cp = C + (size_t)(m0 + ty * 8 + i) * ldc + n0 + tx * 8;
        float4 v0 = {acc[i][0] + bb8[0], acc[i][1] + bb8[1], acc[i][2] + bb8[2], acc[i][3] + bb8[3]};
        float4 v1 = {acc[i][4] + bb8[4], acc[i][5] + bb8[5], acc[i][6] + bb8[6], acc[i][7] + bb8[7]};
        *(float4*)cp = v0;
        *(float4*)(cp + 4) = v1;
    }
}

// ---------------------------------------------------------------- encoder GRU step (both dirs)
// grid = 2 dirs * 8 btiles * 16 jtiles = 256 blocks, 256 thr (32 j-lanes x 8 b)
// xp: (T,B,1536) pre-projected (includes bih). hprev/hnew: (2,B,512). out: (T,B,1024).
__global__ __launch_bounds__(256) void enc_gru_step(const float* __restrict__ xp,
                                                    const float* __restrict__ Ur,
                                                    const float* __restrict__ Uz,
                                                    const float* __restrict__ Un,
                                                    const float* __restrict__ bn,
                                                    const float* __restrict__ hprev,
                                                    float* __restrict__ hnew,
                                                    float* __restrict__ outbuf, int s) {
    const int bid = blockIdx.x;
    const int dir = bid >> 7;
    const int bt = (bid >> 4) & 7;
    const int jt = bid & 15;
    const int j = jt * 32 + (threadIdx.x & 31);
    const int b = bt * 8 + (threadIdx.x >> 5);
    const int t = dir ? (TSE - 1 - s) : s;
    const float* hp = hprev + ((size_t)((dir << 6) + b)) * HH;
    const float* ur = Ur + (size_t)j * HH;
    const float* uz = Uz + (size_t)j * HH;
    const float* un = Un + (size_t)j * HH;
    float ar = 0.f, az = 0.f, an = 0.f;
#pragma unroll 4
    for (int k = 0; k < HH; k += 4) {
        float4 h4 = *(const float4*)(hp + k);
        float4 r4 = *(const float4*)(ur + k);
        float4 z4 = *(const float4*)(uz + k);
        float4 n4 = *(const float4*)(un + k);
        ar += h4.x * r4.x + h4.y * r4.y + h4.z * r4.z + h4.w * r4.w;
        az += h4.x * z4.x + h4.y * z4.y + h4.z * z4.z + h4.w * z4.w;
        an += h4.x * n4.x + h4.y * n4.y + h4.z * n4.z + h4.w * n4.w;
    }
    const float* xpt = xp + ((size_t)t * BB + b) * 1536;
    float r = sigmoidf_(xpt[j] + ar);
    float z = sigmoidf_(xpt[512 + j] + az);
    float n = tanhf(xpt[1024 + j] + r * (an + bn[j]));
    float hv = hp[j];
    float hn = (1.f - z) * n + z * hv;
    hnew[((size_t)((dir << 6) + b)) * HH + j] = hn;
    outbuf[((size_t)t * BB + b) * 1024 + (dir << 9) + j] = hn;
}

// ---------------------------------------------------------------- decoder GRU step (fused ht@Wih_h)
// grid = 8 btiles * 16 jtiles = 128 blocks
__global__ __launch_bounds__(256) void dec_gru_step(const float* __restrict__ xpx,
                                                    const float* __restrict__ Wih,
                                                    const float* __restrict__ Ur,
                                                    const float* __restrict__ Uz,
                                                    const float* __restrict__ Un,
                                                    const float* __restrict__ bn,
                                                    const float* __restrict__ htprev,
                                                    const float* __restrict__ hprev,
                                                    float* __restrict__ hnew, int t) {
    const int bid = blockIdx.x;
    const int bt = bid >> 4, jt = bid & 15;
    const int j = jt * 32 + (threadIdx.x & 31);
    const int b = bt * 8 + (threadIdx.x >> 5);
    const float* hp = hprev + (size_t)b * HH;
    const float* qp = htprev + (size_t)b * HH;
    const float* ur = Ur + (size_t)j * HH;
    const float* uz = Uz + (size_t)j * HH;
    const float* un = Un + (size_t)j * HH;
    const float* wr = Wih + (size_t)j * 1024 + 512;
    const float* wz = Wih + (size_t)(512 + j) * 1024 + 512;
    const float* wn = Wih + (size_t)(1024 + j) * 1024 + 512;
    float ar = 0.f, az = 0.f, an = 0.f, xr = 0.f, xz = 0.f, xn = 0.f;
#pragma unroll 2
    for (int k = 0; k < HH; k += 4) {
        float4 h4 = *(const float4*)(hp + k);
        float4 q4 = *(const float4*)(qp + k);
        float4 r4 = *(const float4*)(ur + k);
        float4 z4 = *(const float4*)(uz + k);
        float4 n4 = *(const float4*)(un + k);
        float4 a4 = *(const float4*)(wr + k);
        float4 b4 = *(const float4*)(wz + k);
        float4 c4 = *(const float4*)(wn + k);
        ar += h4.x * r4.x + h4.y * r4.y + h4.z * r4.z + h4.w * r4.w;
        az += h4.x * z4.x + h4.y * z4.y + h4.z * z4.z + h4.w * z4.w;
        an += h4.x * n4.x + h4.y * n4.y + h4.z * n4.z + h4.w * n4.w;
        xr += q4.x * a4.x + q4.y * a4.y + q4.z * a4.z + q4.w * a4.w;
        xz += q4.x * b4.x + q4.y * b4.y + q4.z * b4.z + q4.w * b4.w;
        xn += q4.x * c4.x + q4.y * c4.y + q4.z * c4.z + q4.w * c4.w;
    }
    const float* xpt = xpx + ((size_t)t * BB + b) * 1536;
    float r = sigmoidf_(xpt[j] + xr + ar);
    float z = sigmoidf_(xpt[512 + j] + xz + az);
    float n = tanhf(xpt[1024 + j] + xn + r * (an + bn[j]));
    float hv = hp[j];
    hnew[(size_t)b * HH + j] = (1.f - z) * n + z * hv;
}

// ---------------------------------------------------------------- attention (scores+softmax+ctx)
// grid = 64 blocks (one per b), 256 thr (4 waves)
__global__ __launch_bounds__(256) void attn_step(const float* __restrict__ h,
                                                 const float* __restrict__ Katt,  // (T,B,512)
                                                 const float* __restrict__ Henc,  // (T,B,1024)
                                                 const int* __restrict__ src,     // (Ts,B)
                                                 float* __restrict__ ctx) {       // (B,1024)
    const int b = blockIdx.x;
    const int tid = threadIdx.x;
    const int lane = tid & 63, w = tid >> 6;
    __shared__ float sc[TSE];
    const float* hb = h + (size_t)b * HH;
    const float4* hp4 = (const float4*)(hb + lane * 8);
    float4 hv0 = hp4[0], hv1 = hp4[1];
    for (int tt = w; tt < TSE; tt += 4) {
        const float4* kp4 = (const float4*)(Katt + ((size_t)tt * BB + b) * HH + lane * 8);
        float4 k0 = kp4[0], k1 = kp4[1];
        float s = k0.x * hv0.x + k0.y * hv0.y + k0.z * hv0.z + k0.w * hv0.w +
                  k1.x * hv1.x + k1.y * hv1.y + k1.z * hv1.z + k1.w * hv1.w;
#pragma unroll
        for (int off = 32; off; off >>= 1) s += __shfl_down(s, off);
        if (lane == 0) {
            float val = s * 0.03125f;  // 1/sqrt(1024)
            if (src[tt * BB + b] == 0) val = -1e9f;
            sc[tt] = val;
        }
    }
    __syncthreads();
    if (tid < 64) {
        float v = (tid < TSE) ? sc[tid] : -3.0e38f;
        float m = v;
#pragma unroll
        for (int off = 32; off; off >>= 1) m = fmaxf(m, __shfl_xor(m, off));
        float e = (tid < TSE) ? expf(v - m) : 0.f;
        float ssum = e;
#pragma unroll
        for (int off = 32; off; off >>= 1) ssum += __shfl_xor(ssum, off);
        if (tid < TSE) sc[tid] = e / ssum;
    }
    __syncthreads();
    for (int d = tid; d < 1024; d += 256) {
        float acc = 0.f;
#pragma unroll 4
        for (int tt = 0; tt < TSE; ++tt) acc += sc[tt] * Henc[((size_t)tt * BB + b) * 1024 + d];
        ctx[(size_t)b * 1024 + d] = acc;
    }
}

// ---------------------------------------------------------------- attn combine: ht = tanh([h,ctx]@Wc^T)
// grid = 128 blocks
__global__ __launch_bounds__(256) void combine_step(const float* __restrict__ h,
                                                    const float* __restrict__ ctx,
                                                    const float* __restrict__ Wc,  // (512,1536)
                                                    float* __restrict__ ht_out) {
    const int bid = blockIdx.x;
    const int bt = bid >> 4, jt = bid & 15;
    const int j = jt * 32 + (threadIdx.x & 31);
    const int b = bt * 8 + (threadIdx.x >> 5);
    const float* hb = h + (size_t)b * HH;
    const float* cb = ctx + (size_t)b * 1024;
    const float* w0 = Wc + (size_t)j * 1536;
    float acc = 0.f;
#pragma unroll 4
    for (int k = 0; k < 512; k += 4) {
        float4 h4 = *(const float4*)(hb + k);
        float4 w4 = *(const float4*)(w0 + k);
        acc += h4.x * w4.x + h4.y * w4.y + h4.z * w4.z + h4.w * w4.w;
    }
#pragma unroll 4
    for (int k = 0; k < 1024; k += 4) {
        float4 c4 = *(const float4*)(cb + k);
        float4 w4 = *(const float4*)(w0 + 512 + k);
        acc += c4.x * w4.x + c4.y * w4.y + c4.z * w4.z + c4.w * w4.w;
    }
    ht_out[(size_t)b * HH + j] = tanhf(acc);
}

// ---------------------------------------------------------------- decoder h0 = tanh([hf,hb]@fcW^T + b)
__global__ __launch_bounds__(256) void fc_init_k(const float* __restrict__ hf,
                                                 const float* __restrict__ hb,
                                                 const float* __restrict__ W,  // (512,1024)
                                                 const float* __restrict__ bias,
                                                 float* __restrict__ h0) {
    const int bid = blockIdx.x;
    const int bt = bid >> 4, jt = bid & 15;
    const int j = jt * 32 + (threadIdx.x & 31);
    const int b = bt * 8 + (threadIdx.x >> 5);
    const float* w0 = W + (size_t)j * 1024;
    float acc = bias[j];
#pragma unroll 4
    for (int k = 0; k < 512; k += 4) {
        float4 h4 = *(const float4*)(hf + (size_t)b * HH + k);
        float4 w4 = *(const float4*)(w0 + k);
        acc += h4.x * w4.x + h4.y * w4.y + h4.z * w4.z + h4.w * w4.w;
    }
#pragma unroll 4
    for (int k = 0; k < 512; k += 4) {
        float4 h4 = *(const float4*)(hb + (size_t)b * HH + k);
        float4 w4 = *(const float4*)(w0 + 512 + k);
        acc += h4.x * w4.x + h4.y * w4.y + h4.z * w4.z + h4.w * w4.w;
    }
    h0[(size_t)b * HH + j] = tanhf(acc);
}

// ----------------------------------------------------------------
extern "C" void kernel_launch(void* const* d_in, const int* in_sizes, int n_in,
                              void* d_out, int out_size, void* d_ws, size_t ws_size,
                              hipStream_t stream) {
    const int* src = (const int*)d_in[0];
    const int* tgt = (const int*)d_in[1];
    const float* emb = (const float*)d_in[2];
    const float* e0Wih = (const float*)d_in[3];
    const float* e0bih = (const float*)d_in[4];
    const float* e0Ur = (const float*)d_in[5];
    const float* e0Uz = (const float*)d_in[6];
    const float* e0Un = (const float*)d_in[7];
    const float* e0bn = (const float*)d_in[8];
    const float* e1Wih = (const float*)d_in[9];
    const float* e1bih = (const float*)d_in[10];
    const float* e1Ur = (const float*)d_in[11];
    const float* e1Uz = (const float*)d_in[12];
    const float* e1Un = (const float*)d_in[13];
    const float* e1bn = (const float*)d_in[14];
    const float* fcW = (const float*)d_in[15];
    const float* fcB = (const float*)d_in[16];
    const float* Wa = (const float*)d_in[17];
    const float* Wc = (const float*)d_in[18];
    const float* dWih = (const float*)d_in[19];
    const float* dbih = (const float*)d_in[20];
    const float* dUr = (const float*)d_in[21];
    const float* dUz = (const float*)d_in[22];
    const float* dUn = (const float*)d_in[23];
    const float* dbn = (const float*)d_in[24];
    const float* outW = (const float*)d_in[25];
    float* out = (float*)d_out;
    float* w = (float*)d_ws;

    // workspace layout (floats); total 19,169,280 floats = 73.1 MB
    float* x_buf = w;                  // 3072*512   (x_src, later x_tgt)
    float* xp01 = w + 1572864;         // 3072*1536  (xp0, later xp1)
    float* l0 = w + 6291456;           // 3072*1024  (l0, later K_att (3072*512))
    float* Henc = w + 9437184;         // 3072*1024
    float* xp_x = w + 12582912;        // 3072*1536
    float* ht_all = w + 17301504;      // 3072*512
    float* enc_h = w + 18874368;       // 2(pp)*2(dir)*64*512
    float* dec_h = w + 19005440;       // 2(pp)*64*512
    float* ht_zero = w + 19070976;     // 64*512
    float* ctx = w + 19103744;         // 64*1024
    if (ws_size < (size_t)19169280 * 4) return;  // insufficient scratch -> visible mismatch

    zero_f32<<<256, 256, 0, stream>>>(enc_h, 65536);
    zero_f32<<<128, 256, 0, stream>>>(ht_zero, 32768);

    // ---- encoder ----
    gather_emb<<<3072, 128, 0, stream>>>(src, emb, x_buf);
    (gemm_f32<1, 1>)<<<dim3(12, 24), 256, 0, stream>>>(x_buf, e0Wih, e0bih, xp01,
                                                       3072, 1536, 512, 512, 512, 1536);
    for (int s = 0; s < TSE; s++)
        enc_gru_step<<<256, 256, 0, stream>>>(xp01, e0Ur, e0Uz, e0Un, e0bn,
                                              enc_h + (s & 1) * 65536,
                                              enc_h + ((s + 1) & 1) * 65536, l0, s);
    gather_emb<<<3072, 128, 0, stream>>>(tgt, emb, x_buf);  // reuse x_buf for tgt
    (gemm_f32<1, 1>)<<<dim3(12, 24), 256, 0, stream>>>(l0, e1Wih, e1bih, xp01,
                                                       3072, 1536, 1024, 1024, 1024, 1536);
    zero_f32<<<256, 256, 0, stream>>>(enc_h, 65536);
    for (int s = 0; s < TSE; s++)
        enc_gru_step<<<256, 256, 0, stream>>>(xp01, e1Ur, e1Uz, e1Un, e1bn,
                                              enc_h + (s & 1) * 65536,
                                              enc_h + ((s + 1) & 1) * 65536, Henc, s);
    // final states (after 48 steps) are in pp0: dir0 = hf, dir1 = hb
    fc_init_k<<<128, 256, 0, stream>>>(enc_h, enc_h + 32768, fcW, fcB, dec_h);

    // K_att = Henc @ Wa  (into l0 region)
    (gemm_f32<0, 0>)<<<dim3(4, 24), 256, 0, stream>>>(Henc, Wa, nullptr, l0,
                                                      3072, 512, 1024, 1024, 512, 512);
    // xp_x = tgt_emb @ dec_Wih[:, :512]^T + dbih
    (gemm_f32<1, 1>)<<<dim3(12, 24), 256, 0, stream>>>(x_buf, dWih, dbih, xp_x,
                                                       3072, 1536, 512, 512, 1024, 1536);

    // ---- decoder ----
    for (int t = 0; t < TTD; t++) {
        const float* htp = (t == 0) ? ht_zero : (ht_all + (size_t)(t - 1) * 32768);
        float* hcur = dec_h + (t & 1) * 32768;
        float* hnext = dec_h + ((t + 1) & 1) * 32768;
        dec_gru_step<<<128, 256, 0, stream>>>(xp_x, dWih, dUr, dUz, dUn, dbn, htp, hcur, hnext, t);
        attn_step<<<64, 256, 0, stream>>>(hnext, l0, Henc, src, ctx);
        combine_step<<<128, 256, 0, stream>>>(hnext, ctx, Wc, ht_all + (size_t)t * 32768);
    }

    // ---- logits: (3072,512) @ (32000,512)^T -> d_out (Tt,B,V) ----
    (gemm_f32<1, 0>)<<<dim3(250, 24), 256, 0, stream>>>(ht_all, outW, nullptr, out,
                                                        3072, 32000, 512, 512, 512, 32000);
}

// Round 3
// 14188.951 us; speedup vs baseline: 1.0769x; 1.0769x over previous
//
#include <hip/hip_runtime.h>
#include <math.h>

// Sizes (fixed by the problem)
#define TSE 48
#define TTD 48
#define BB  64
#define HH  512
#define VV  32000

__device__ __forceinline__ float sigmoidf_(float x) { return 1.0f / (1.0f + expf(-x)); }

__device__ __forceinline__ ushort f2bf(float x) {
    uint u = __float_as_uint(x);
    u += 0x7FFF + ((u >> 16) & 1);
    return (ushort)(u >> 16);
}
__device__ __forceinline__ float bf2f(ushort h) { return __uint_as_float(((uint)h) << 16); }

typedef __attribute__((ext_vector_type(8))) __bf16 bf16x8;
typedef __attribute__((ext_vector_type(4))) float f32x4;

// ---------------------------------------------------------------- zero
__global__ __launch_bounds__(256) void zero_f32(float* __restrict__ p, int n) {
    int i = blockIdx.x * 256 + threadIdx.x;
    if (i < n) p[i] = 0.0f;
}

// ---------------------------------------------------------------- embedding gather
__global__ __launch_bounds__(128) void gather_emb(const int* __restrict__ idx,
                                                  const float* __restrict__ emb,
                                                  float* __restrict__ out) {
    int row = blockIdx.x;
    int v = idx[row];
    const float4* s = (const float4*)(emb + (size_t)v * HH);
    float4* d = (float4*)(out + (size_t)row * HH);
    d[threadIdx.x] = s[threadIdx.x];
}

// ---------------------------------------------------------------- f32 -> bf16 hi/lo split (packed, 4/thread)
__global__ __launch_bounds__(256) void split4(const float* __restrict__ in,
                                              ushort* __restrict__ hi, ushort* __restrict__ lo, int n) {
    int i = (blockIdx.x * 256 + threadIdx.x) * 4;
    if (i >= n) return;
    float4 v = *(const float4*)(in + i);
    ushort h0 = f2bf(v.x), h1 = f2bf(v.y), h2 = f2bf(v.z), h3 = f2bf(v.w);
    ushort4 H = {h0, h1, h2, h3};
    ushort4 L = {f2bf(v.x - bf2f(h0)), f2bf(v.y - bf2f(h1)), f2bf(v.z - bf2f(h2)), f2bf(v.w - bf2f(h3))};
    *(ushort4*)(hi + i) = H;
    *(ushort4*)(lo + i) = L;
}

// split of dWih[:, :512] (ld=1024) -> packed 1536x512
__global__ __launch_bounds__(256) void split4_dwx(const float* __restrict__ in,
                                                  ushort* __restrict__ hi, ushort* __restrict__ lo, int n) {
    int i = (blockIdx.x * 256 + threadIdx.x) * 4;
    if (i >= n) return;
    int r = i >> 9, c = i & 511;
    float4 v = *(const float4*)(in + (size_t)r * 1024 + c);
    ushort h0 = f2bf(v.x), h1 = f2bf(v.y), h2 = f2bf(v.z), h3 = f2bf(v.w);
    ushort4 H = {h0, h1, h2, h3};
    ushort4 L = {f2bf(v.x - bf2f(h0)), f2bf(v.y - bf2f(h1)), f2bf(v.z - bf2f(h2)), f2bf(v.w - bf2f(h3))};
    *(ushort4*)(hi + i) = H;
    *(ushort4*)(lo + i) = L;
}

// WaT[e][d] = Wa[d][e]; Wa (1024,512) -> packed (512,1024) bf16 hi/lo
__global__ __launch_bounds__(256) void split_waT(const float* __restrict__ Wa,
                                                 ushort* __restrict__ hi, ushort* __restrict__ lo) {
    int o = blockIdx.x * 256 + threadIdx.x;  // 524288
    int e = o >> 10, d = o & 1023;
    float v = Wa[(size_t)d * 512 + e];
    ushort h = f2bf(v);
    hi[o] = h;
    lo[o] = f2bf(v - bf2f(h));
}

// ---------------------------------------------------------------- MFMA split-bf16 GEMM
// C[M,N] = (Ahi+Alo)[M,K] @ (Bhi+Blo)[N,K]^T (+bias), 3-pass (drop lo*lo).
// 128x128 tile, BK=32, 4 waves: wave w stages buffer w via global_load_lds(16B).
template <int BIAS>
__global__ __launch_bounds__(256, 2) void gemm_mfma(const ushort* __restrict__ Ahi,
                                                    const ushort* __restrict__ Alo,
                                                    const ushort* __restrict__ Bhi,
                                                    const ushort* __restrict__ Blo,
                                                    const float* __restrict__ bias,
                                                    float* __restrict__ C,
                                                    int K, int ldc) {
    __shared__ ushort sA[2][128 * 32];
    __shared__ ushort sB[2][128 * 32];
    const int tid = threadIdx.x;
    const int wid = tid >> 6, lane = tid & 63;
    const int m0 = blockIdx.y << 7, n0 = blockIdx.x << 7;

    const ushort* gb;
    ushort* lb;
    switch (wid) {
        case 0: gb = Ahi + (size_t)m0 * K; lb = sA[0]; break;
        case 1: gb = Alo + (size_t)m0 * K; lb = sA[1]; break;
        case 2: gb = Bhi + (size_t)n0 * K; lb = sB[0]; break;
        default: gb = Blo + (size_t)n0 * K; lb = sB[1]; break;
    }
    gb += (size_t)(lane >> 2) * K + (lane & 3) * 8;

    const int wr = (wid >> 1) << 6, wc = (wid & 1) << 6;
    const int frow = lane & 15, fk = (lane >> 4) << 3;
    f32x4 acc[4][4];
#pragma unroll
    for (int i = 0; i < 4; i++)
#pragma unroll
        for (int j = 0; j < 4; j++) acc[i][j] = (f32x4){0.f, 0.f, 0.f, 0.f};

    for (int k0 = 0; k0 < K; k0 += 32) {
        __syncthreads();
#pragma unroll
        for (int c = 0; c < 8; ++c)
            __builtin_amdgcn_global_load_lds(
                (const __attribute__((address_space(1))) void*)(gb + k0 + (size_t)(c << 4) * K),
                (__attribute__((address_space(3))) void*)(lb + (c << 9)), 16, 0, 0);
        __syncthreads();
        bf16x8 ah[4], al[4], bh[4], bl[4];
#pragma unroll
        for (int i = 0; i < 4; ++i) {
            ah[i] = *(const bf16x8*)&sA[0][((wr + (i << 4) + frow) << 5) + fk];
            al[i] = *(const bf16x8*)&sA[1][((wr + (i << 4) + frow) << 5) + fk];
            bh[i] = *(const bf16x8*)&sB[0][((wc + (i << 4) + frow) << 5) + fk];
            bl[i] = *(const bf16x8*)&sB[1][((wc + (i << 4) + frow) << 5) + fk];
        }
#pragma unroll
        for (int i = 0; i < 4; ++i)
#pragma unroll
            for (int j = 0; j < 4; ++j) {
                acc[i][j] = __builtin_amdgcn_mfma_f32_16x16x32_bf16(ah[i], bh[j], acc[i][j], 0, 0, 0);
                acc[i][j] = __builtin_amdgcn_mfma_f32_16x16x32_bf16(al[i], bh[j], acc[i][j], 0, 0, 0);
                acc[i][j] = __builtin_amdgcn_mfma_f32_16x16x32_bf16(ah[i], bl[j], acc[i][j], 0, 0, 0);
            }
    }
    const int crow = (lane >> 4) << 2, ccol = lane & 15;
#pragma unroll
    for (int j = 0; j < 4; ++j) {
        int n = n0 + wc + (j << 4) + ccol;
        float bv = BIAS ? bias[n] : 0.f;
#pragma unroll
        for (int i = 0; i < 4; ++i) {
            float* cp = C + (size_t)(m0 + wr + (i << 4) + crow) * ldc + n;
#pragma unroll
            for (int r = 0; r < 4; ++r) cp[(size_t)r * ldc] = acc[i][j][r] + bv;
        }
    }
}

// ---------------------------------------------------------------- f32 GEMM (fallback path)
template <int TRANSB, int BIAS>
__global__ __launch_bounds__(256) void gemm_f32(const float* __restrict__ A,
                                                const float* __restrict__ Bm,
                                                const float* __restrict__ bias,
                                                float* __restrict__ C,
                                                int M, int N, int K, int lda, int ldb, int ldc) {
    __shared__ float As[32][132];
    __shared__ float Bs[32][132];
    const int tid = threadIdx.x;
    const int tx = tid & 15, ty = tid >> 4;
    const int m0 = blockIdx.y * 128, n0 = blockIdx.x * 128;

    float acc[8][8];
#pragma unroll
    for (int i = 0; i < 8; i++)
#pragma unroll
        for (int j = 0; j < 8; j++) acc[i][j] = 0.0f;

    const int arow = tid >> 1, akq = (tid & 1) * 16;
    const int bk = tid >> 3, bnq = (tid & 7) * 16;

    for (int k0 = 0; k0 < K; k0 += 32) {
        float4 av[4], bv[4];
        const float* ap = A + (size_t)(m0 + arow) * lda + k0 + akq;
#pragma unroll
        for (int q = 0; q < 4; q++) av[q] = *(const float4*)(ap + 4 * q);
        if (TRANSB) {
            const float* bp = Bm + (size_t)(n0 + arow) * ldb + k0 + akq;
#pragma unroll
            for (int q = 0; q < 4; q++) bv[q] = *(const float4*)(bp + 4 * q);
        } else {
            const float* bp = Bm + (size_t)(k0 + bk) * ldb + n0 + bnq;
#pragma unroll
            for (int q = 0; q < 4; q++) bv[q] = *(const float4*)(bp + 4 * q);
        }
        __syncthreads();
#pragma unroll
        for (int q = 0; q < 4; q++) {
            As[akq + 4 * q + 0][arow] = av[q].x;
            As[akq + 4 * q + 1][arow] = av[q].y;
            As[akq + 4 * q + 2][arow] = av[q].z;
            As[akq + 4 * q + 3][arow] = av[q].w;
        }
        if (TRANSB) {
#pragma unroll
            for (int q = 0; q < 4; q++) {
                Bs[akq + 4 * q + 0][arow] = bv[q].x;
                Bs[akq + 4 * q + 1][arow] = bv[q].y;
                Bs[akq + 4 * q + 2][arow] = bv[q].z;
                Bs[akq + 4 * q + 3][arow] = bv[q].w;
            }
        } else {
#pragma unroll
            for (int q = 0; q < 4; q++) *(float4*)&Bs[bk][bnq + 4 * q] = bv[q];
        }
        __syncthreads();
#pragma unroll
        for (int kk = 0; kk < 32; kk++) {
            float4 a0 = *(const float4*)&As[kk][ty * 8];
            float4 a1 = *(const float4*)&As[kk][ty * 8 + 4];
            float4 b0 = *(const float4*)&Bs[kk][tx * 8];
            float4 b1 = *(const float4*)&Bs[kk][tx * 8 + 4];
            float aa[8] = {a0.x, a0.y, a0.z, a0.w, a1.x, a1.y, a1.z, a1.w};
            float bb[8] = {b0.x, b0.y, b0.z, b0.w, b1.x, b1.y, b1.z, b1.w};
#pragma unroll
            for (int i = 0; i < 8; i++)
#pragma unroll
                for (int j = 0; j < 8; j++) acc[i][j] += aa[i] * bb[j];
        }
    }

    float bb8[8];
#pragma unroll
    for (int j = 0; j < 8; j++) bb8[j] = BIAS ? bias[n0 + tx * 8 + j] : 0.0f;
#pragma unroll
    for (int i = 0; i < 8; i++) {
        float* cp = C + (size_t)(m0 + ty * 8 + i) * ldc + n0 + tx * 8;
        float4 v0 = {acc[i][0] + bb8[0], acc[i][1] + bb8[1], acc[i][2] + bb8[2], acc[i][3] + bb8[3]};
        float4 v1 = {acc[i][4] + bb8[4], acc[i][5] + bb8[5], acc[i][6] + bb8[6], acc[i][7] + bb8[7]};
        *(float4*)cp = v0;
        *(float4*)(cp + 4) = v1;
    }
}

// ---------------------------------------------------------------- encoder GRU step (both dirs)
__global__ __launch_bounds__(256) void enc_gru_step(const float* __restrict__ xp,
                                                    const float* __restrict__ Ur,
                                                    const float* __restrict__ Uz,
                                                    const float* __restrict__ Un,
                                                    const float* __restrict__ bn,
                                                    const float* __restrict__ hprev,
                                                    float* __restrict__ hnew,
                                                    float* __restrict__ outbuf, int s) {
    const int bid = blockIdx.x;
    const int dir = bid >> 7;
    const int bt = (bid >> 4) & 7;
    const int jt = bid & 15;
    const int j = jt * 32 + (threadIdx.x & 31);
    const int b = bt * 8 + (threadIdx.x >> 5);
    const int t = dir ? (TSE - 1 - s) : s;
    const float* hp = hprev + ((size_t)((dir << 6) + b)) * HH;
    const float* ur = Ur + (size_t)j * HH;
    const float* uz = Uz + (size_t)j * HH;
    const float* un = Un + (size_t)j * HH;
    float ar = 0.f, az = 0.f, an = 0.f;
#pragma unroll 4
    for (int k = 0; k < HH; k += 4) {
        float4 h4 = *(const float4*)(hp + k);
        float4 r4 = *(const float4*)(ur + k);
        float4 z4 = *(const float4*)(uz + k);
        float4 n4 = *(const float4*)(un + k);
        ar += h4.x * r4.x + h4.y * r4.y + h4.z * r4.z + h4.w * r4.w;
        az += h4.x * z4.x + h4.y * z4.y + h4.z * z4.z + h4.w * z4.w;
        an += h4.x * n4.x + h4.y * n4.y + h4.z * n4.z + h4.w * n4.w;
    }
    const float* xpt = xp + ((size_t)t * BB + b) * 1536;
    float r = sigmoidf_(xpt[j] + ar);
    float z = sigmoidf_(xpt[512 + j] + az);
    float n = tanhf(xpt[1024 + j] + r * (an + bn[j]));
    float hv = hp[j];
    float hn = (1.f - z) * n + z * hv;
    hnew[((size_t)((dir << 6) + b)) * HH + j] = hn;
    outbuf[((size_t)t * BB + b) * 1024 + (dir << 9) + j] = hn;
}

// ---------------------------------------------------------------- decoder GRU step
__global__ __launch_bounds__(256) void dec_gru_step(const float* __restrict__ xpx,
                                                    const float* __restrict__ Wih,
                                                    const float* __restrict__ Ur,
                                                    const float* __restrict__ Uz,
                                                    const float* __restrict__ Un,
                                                    const float* __restrict__ bn,
                                                    const float* __restrict__ htprev,
                                                    const float* __restrict__ hprev,
                                                    float* __restrict__ hnew, int t) {
    const int bid = blockIdx.x;
    const int bt = bid >> 4, jt = bid & 15;
    const int j = jt * 32 + (threadIdx.x & 31);
    const int b = bt * 8 + (threadIdx.x >> 5);
    const float* hp = hprev + (size_t)b * HH;
    const float* qp = htprev + (size_t)b * HH;
    const float* ur = Ur + (size_t)j * HH;
    const float* uz = Uz + (size_t)j * HH;
    const float* un = Un + (size_t)j * HH;
    const float* wr = Wih + (size_t)j * 1024 + 512;
    const float* wz = Wih + (size_t)(512 + j) * 1024 + 512;
    const float* wn = Wih + (size_t)(1024 + j) * 1024 + 512;
    float ar = 0.f, az = 0.f, an = 0.f, xr = 0.f, xz = 0.f, xn = 0.f;
#pragma unroll 2
    for (int k = 0; k < HH; k += 4) {
        float4 h4 = *(const float4*)(hp + k);
        float4 q4 = *(const float4*)(qp + k);
        float4 r4 = *(const float4*)(ur + k);
        float4 z4 = *(const float4*)(uz + k);
        float4 n4 = *(const float4*)(un + k);
        float4 a4 = *(const float4*)(wr + k);
        float4 b4 = *(const float4*)(wz + k);
        float4 c4 = *(const float4*)(wn + k);
        ar += h4.x * r4.x + h4.y * r4.y + h4.z * r4.z + h4.w * r4.w;
        az += h4.x * z4.x + h4.y * z4.y + h4.z * z4.z + h4.w * z4.w;
        an += h4.x * n4.x + h4.y * n4.y + h4.z * n4.z + h4.w * n4.w;
        xr += q4.x * a4.x + q4.y * a4.y + q4.z * a4.z + q4.w * a4.w;
        xz += q4.x * b4.x + q4.y * b4.y + q4.z * b4.z + q4.w * b4.w;
        xn += q4.x * c4.x + q4.y * c4.y + q4.z * c4.z + q4.w * c4.w;
    }
    const float* xpt = xpx + ((size_t)t * BB + b) * 1536;
    float r = sigmoidf_(xpt[j] + xr + ar);
    float z = sigmoidf_(xpt[512 + j] + xz + az);
    float n = tanhf(xpt[1024 + j] + xn + r * (an + bn[j]));
    float hv = hp[j];
    hnew[(size_t)b * HH + j] = (1.f - z) * n + z * hv;
}

// ---------------------------------------------------------------- attention
__global__ __launch_bounds__(256) void attn_step(const float* __restrict__ h,
                                                 const float* __restrict__ Katt,
                                                 const float* __restrict__ Henc,
                                                 const int* __restrict__ src,
                                                 float* __restrict__ ctx) {
    const int b = blockIdx.x;
    const int tid = threadIdx.x;
    const int lane = tid & 63, w = tid >> 6;
    __shared__ float sc[TSE];
    const float* hb = h + (size_t)b * HH;
    const float4* hp4 = (const float4*)(hb + lane * 8);
    float4 hv0 = hp4[0], hv1 = hp4[1];
    for (int tt = w; tt < TSE; tt += 4) {
        const float4* kp4 = (const float4*)(Katt + ((size_t)tt * BB + b) * HH + lane * 8);
        float4 k0 = kp4[0], k1 = kp4[1];
        float s = k0.x * hv0.x + k0.y * hv0.y + k0.z * hv0.z + k0.w * hv0.w +
                  k1.x * hv1.x + k1.y * hv1.y + k1.z * hv1.z + k1.w * hv1.w;
#pragma unroll
        for (int off = 32; off; off >>= 1) s += __shfl_down(s, off);
        if (lane == 0) {
            float val = s * 0.03125f;
            if (src[tt * BB + b] == 0) val = -1e9f;
            sc[tt] = val;
        }
    }
    __syncthreads();
    if (tid < 64) {
        float v = (tid < TSE) ? sc[tid] : -3.0e38f;
        float m = v;
#pragma unroll
        for (int off = 32; off; off >>= 1) m = fmaxf(m, __shfl_xor(m, off));
        float e = (tid < TSE) ? expf(v - m) : 0.f;
        float ssum = e;
#pragma unroll
        for (int off = 32; off; off >>= 1) ssum += __shfl_xor(ssum, off);
        if (tid < TSE) sc[tid] = e / ssum;
    }
    __syncthreads();
    for (int d = tid; d < 1024; d += 256) {
        float acc = 0.f;
#pragma unroll 4
        for (int tt = 0; tt < TSE; ++tt) acc += sc[tt] * Henc[((size_t)tt * BB + b) * 1024 + d];
        ctx[(size_t)b * 1024 + d] = acc;
    }
}

// ---------------------------------------------------------------- attn combine
__global__ __launch_bounds__(256) void combine_step(const float* __restrict__ h,
                                                    const float* __restrict__ ctx,
                                                    const float* __restrict__ Wc,
                                                    float* __restrict__ ht_out) {
    const int bid = blockIdx.x;
    const int bt = bid >> 4, jt = bid & 15;
    const int j = jt * 32 + (threadIdx.x & 31);
    const int b = bt * 8 + (threadIdx.x >> 5);
    const float* hb = h + (size_t)b * HH;
    const float* cb = ctx + (size_t)b * 1024;
    const float* w0 = Wc + (size_t)j * 1536;
    float acc = 0.f;
#pragma unroll 4
    for (int k = 0; k < 512; k += 4) {
        float4 h4 = *(const float4*)(hb + k);
        float4 w4 = *(const float4*)(w0 + k);
        acc += h4.x * w4.x + h4.y * w4.y + h4.z * w4.z + h4.w * w4.w;
    }
#pragma unroll 4
    for (int k = 0; k < 1024; k += 4) {
        float4 c4 = *(const float4*)(cb + k);
        float4 w4 = *(const float4*)(w0 + 512 + k);
        acc += c4.x * w4.x + c4.y * w4.y + c4.z * w4.z + c4.w * w4.w;
    }
    ht_out[(size_t)b * HH + j] = tanhf(acc);
}

// ---------------------------------------------------------------- decoder h0
__global__ __launch_bounds__(256) void fc_init_k(const float* __restrict__ hf,
                                                 const float* __restrict__ hb,
                                                 const float* __restrict__ W,
                                                 const float* __restrict__ bias,
                                                 float* __restrict__ h0) {
    const int bid = blockIdx.x;
    const int bt = bid >> 4, jt = bid & 15;
    const int j = jt * 32 + (threadIdx.x & 31);
    const int b = bt * 8 + (threadIdx.x >> 5);
    const float* w0 = W + (size_t)j * 1024;
    float acc = bias[j];
#pragma unroll 4
    for (int k = 0; k < 512; k += 4) {
        float4 h4 = *(const float4*)(hf + (size_t)b * HH + k);
        float4 w4 = *(const float4*)(w0 + k);
        acc += h4.x * w4.x + h4.y * w4.y + h4.z * w4.z + h4.w * w4.w;
    }
#pragma unroll 4
    for (int k = 0; k < 512; k += 4) {
        float4 h4 = *(const float4*)(hb + (size_t)b * HH + k);
        float4 w4 = *(const float4*)(w0 + 512 + k);
        acc += h4.x * w4.x + h4.y * w4.y + h4.z * w4.z + h4.w * w4.w;
    }
    h0[(size_t)b * HH + j] = tanhf(acc);
}

// ----------------------------------------------------------------
extern "C" void kernel_launch(void* const* d_in, const int* in_sizes, int n_in,
                              void* d_out, int out_size, void* d_ws, size_t ws_size,
                              hipStream_t stream) {
    const int* src = (const int*)d_in[0];
    const int* tgt = (const int*)d_in[1];
    const float* emb = (const float*)d_in[2];
    const float* e0Wih = (const float*)d_in[3];
    const float* e0bih = (const float*)d_in[4];
    const float* e0Ur = (const float*)d_in[5];
    const float* e0Uz = (const float*)d_in[6];
    const float* e0Un = (const float*)d_in[7];
    const float* e0bn = (const float*)d_in[8];
    const float* e1Wih = (const float*)d_in[9];
    const float* e1bih = (const float*)d_in[10];
    const float* e1Ur = (const float*)d_in[11];
    const float* e1Uz = (const float*)d_in[12];
    const float* e1Un = (const float*)d_in[13];
    const float* e1bn = (const float*)d_in[14];
    const float* fcW = (const float*)d_in[15];
    const float* fcB = (const float*)d_in[16];
    const float* Wa = (const float*)d_in[17];
    const float* Wc = (const float*)d_in[18];
    const float* dWih = (const float*)d_in[19];
    const float* dbih = (const float*)d_in[20];
    const float* dUr = (const float*)d_in[21];
    const float* dUz = (const float*)d_in[22];
    const float* dUn = (const float*)d_in[23];
    const float* dbn = (const float*)d_in[24];
    const float* outW = (const float*)d_in[25];
    float* out = (float*)d_out;
    float* w = (float*)d_ws;

    // ---- f32 workspace (floats), 19,169,280 floats = 76.7 MB ----
    float* x_buf = w;                  // 3072*512   [dead after its split / GEMM]
    float* xp01 = w + 1572864;         // 3072*1536
    float* l0 = w + 6291456;           // 3072*1024 (layer1 out, later Katt)
    float* Henc = w + 9437184;         // 3072*1024
    float* xp_x = w + 12582912;        // 3072*1536
    float* ht_all = w + 17301504;      // 3072*512
    float* enc_h = w + 18874368;       // 2*2*64*512
    float* dec_h = w + 19005440;       // 2*64*512
    float* ht_zero = w + 19070976;     // 64*512
    float* ctx = w + 19103744;         // 64*1024
    if (ws_size < (size_t)19169280 * 4) return;

    zero_f32<<<256, 256, 0, stream>>>(enc_h, 65536);
    zero_f32<<<128, 256, 0, stream>>>(ht_zero, 32768);

    // bf16 region after f32: small weight splits + activation splits = 27.3 MB.
    // outW hi/lo (65.5 MB) is aliased over w[0 .. 16,384,000 floats) — the
    // x_buf/xp01/l0/Henc/xp_x region, all dead after the decoder loop — and
    // split LATE. Peak footprint: 103,940,096 bytes.
    const bool use_mfma = ws_size >= (size_t)103940096;

    if (use_mfma) {
        ushort* u = (ushort*)(w + 19169280);
        ushort* e0hi = u;                  // 1536*512
        ushort* e0lo = u + 786432;
        ushort* e1hi = u + 1572864;        // 1536*1024
        ushort* e1lo = u + 3145728;
        ushort* wahi = u + 4718592;        // 512*1024
        ushort* walo = u + 5242880;
        ushort* dxhi = u + 5767168;        // 1536*512
        ushort* dxlo = u + 6553600;
        ushort* Ahi = u + 7340032;         // 3072*1024 (activation splits, reused)
        ushort* Alo = u + 10485760;        // ends 13,631,488 ushorts

        // small weight splits
        split4<<<768, 256, 0, stream>>>(e0Wih, e0hi, e0lo, 786432);
        split4<<<1536, 256, 0, stream>>>(e1Wih, e1hi, e1lo, 1572864);
        split_waT<<<2048, 256, 0, stream>>>(Wa, wahi, walo);
        split4_dwx<<<768, 256, 0, stream>>>(dWih, dxhi, dxlo, 786432);

        // ---- encoder ----
        gather_emb<<<3072, 128, 0, stream>>>(src, emb, x_buf);
        split4<<<1536, 256, 0, stream>>>(x_buf, Ahi, Alo, 1572864);
        (gemm_mfma<1>)<<<dim3(12, 24), 256, 0, stream>>>(Ahi, Alo, e0hi, e0lo, e0bih, xp01, 512, 1536);
        for (int s = 0; s < TSE; s++)
            enc_gru_step<<<256, 256, 0, stream>>>(xp01, e0Ur, e0Uz, e0Un, e0bn,
                                                  enc_h + (s & 1) * 65536,
                                                  enc_h + ((s + 1) & 1) * 65536, l0, s);
        gather_emb<<<3072, 128, 0, stream>>>(tgt, emb, x_buf);  // x_buf now tgt emb
        split4<<<3072, 256, 0, stream>>>(l0, Ahi, Alo, 3145728);
        (gemm_mfma<1>)<<<dim3(12, 24), 256, 0, stream>>>(Ahi, Alo, e1hi, e1lo, e1bih, xp01, 1024, 1536);
        zero_f32<<<256, 256, 0, stream>>>(enc_h, 65536);
        for (int s = 0; s < TSE; s++)
            enc_gru_step<<<256, 256, 0, stream>>>(xp01, e1Ur, e1Uz, e1Un, e1bn,
                                                  enc_h + (s & 1) * 65536,
                                                  enc_h + ((s + 1) & 1) * 65536, Henc, s);
        fc_init_k<<<128, 256, 0, stream>>>(enc_h, enc_h + 32768, fcW, fcB, dec_h);

        // K_att = Henc @ Wa (into l0)
        split4<<<3072, 256, 0, stream>>>(Henc, Ahi, Alo, 3145728);
        (gemm_mfma<0>)<<<dim3(4, 24), 256, 0, stream>>>(Ahi, Alo, wahi, walo, nullptr, l0, 1024, 512);
        // xp_x = tgt_emb @ dWih[:, :512]^T + dbih
        split4<<<1536, 256, 0, stream>>>(x_buf, Ahi, Alo, 1572864);
        (gemm_mfma<1>)<<<dim3(12, 24), 256, 0, stream>>>(Ahi, Alo, dxhi, dxlo, dbih, xp_x, 512, 1536);

        // ---- decoder ----
        for (int t = 0; t < TTD; t++) {
            const float* htp = (t == 0) ? ht_zero : (ht_all + (size_t)(t - 1) * 32768);
            float* hcur = dec_h + (t & 1) * 32768;
            float* hnext = dec_h + ((t + 1) & 1) * 32768;
            dec_gru_step<<<128, 256, 0, stream>>>(xp_x, dWih, dUr, dUz, dUn, dbn, htp, hcur, hnext, t);
            attn_step<<<64, 256, 0, stream>>>(hnext, l0, Henc, src, ctx);
            combine_step<<<128, 256, 0, stream>>>(hnext, ctx, Wc, ht_all + (size_t)t * 32768);
        }

        // ---- late outW split over dead f32 region, then logits ----
        ushort* oWhi = (ushort*)w;                 // 32000*512
        ushort* oWlo = (ushort*)(w + 8192000);
        split4<<<16000, 256, 0, stream>>>(outW, oWhi, oWlo, 16384000);
        split4<<<1536, 256, 0, stream>>>(ht_all, Ahi, Alo, 1572864);
        (gemm_mfma<0>)<<<dim3(250, 24), 256, 0, stream>>>(Ahi, Alo, oWhi, oWlo, nullptr, out, 512, 32000);
    } else {
        // ---------------- fallback: proven f32 path (round 1) ----------------
        gather_emb<<<3072, 128, 0, stream>>>(src, emb, x_buf);
        (gemm_f32<1, 1>)<<<dim3(12, 24), 256, 0, stream>>>(x_buf, e0Wih, e0bih, xp01,
                                                           3072, 1536, 512, 512, 512, 1536);
        for (int s = 0; s < TSE; s++)
            enc_gru_step<<<256, 256, 0, stream>>>(xp01, e0Ur, e0Uz, e0Un, e0bn,
                                                  enc_h + (s & 1) * 65536,
                                                  enc_h + ((s + 1) & 1) * 65536, l0, s);
        gather_emb<<<3072, 128, 0, stream>>>(tgt, emb, x_buf);
        (gemm_f32<1, 1>)<<<dim3(12, 24), 256, 0, stream>>>(l0, e1Wih, e1bih, xp01,
                                                           3072, 1536, 1024, 1024, 1024, 1536);
        zero_f32<<<256, 256, 0, stream>>>(enc_h, 65536);
        for (int s = 0; s < TSE; s++)
            enc_gru_step<<<256, 256, 0, stream>>>(xp01, e1Ur, e1Uz, e1Un, e1bn,
                                                  enc_h + (s & 1) * 65536,
                                                  enc_h + ((s + 1) & 1) * 65536, Henc, s);
        fc_init_k<<<128, 256, 0, stream>>>(enc_h, enc_h + 32768, fcW, fcB, dec_h);

        (gemm_f32<0, 0>)<<<dim3(4, 24), 256, 0, stream>>>(Henc, Wa, nullptr, l0,
                                                          3072, 512, 1024, 1024, 512, 512);
        (gemm_f32<1, 1>)<<<dim3(12, 24), 256, 0, stream>>>(x_buf, dWih, dbih, xp_x,
                                                           3072, 1536, 512, 512, 1024, 1536);

        for (int t = 0; t < TTD; t++) {
            const float* htp = (t == 0) ? ht_zero : (ht_all + (size_t)(t - 1) * 32768);
            float* hcur = dec_h + (t & 1) * 32768;
            float* hnext = dec_h + ((t + 1) & 1) * 32768;
            dec_gru_step<<<128, 256, 0, stream>>>(xp_x, dWih, dUr, dUz, dUn, dbn, htp, hcur, hnext, t);
            attn_step<<<64, 256, 0, stream>>>(hnext, l0, Henc, src, ctx);
            combine_step<<<128, 256, 0, stream>>>(hnext, ctx, Wc, ht_all + (size_t)t * 32768);
        }

        (gemm_f32<1, 0>)<<<dim3(250, 24), 256, 0, stream>>>(ht_all, outW, nullptr, out,
                                                            3072, 32000, 512, 512, 512, 32000);
    }
}